// Round 1
// baseline (584.740 us; speedup 1.0000x reference)
//
#include <hip/hip_runtime.h>
#include <hip/hip_bf16.h>

#define NSPK 1024
#define MU 32
#define DIM 512
#define EPS 1e-6f

// ---------------------------------------------------------------------------
// Kernel 1: per-speaker sums -> normalized transposed centroids, LOO cosines,
// inverse utterance norms.
// grid = NSPK, block = 256
// ---------------------------------------------------------------------------
__global__ __launch_bounds__(256) void k_prep(
    const float* __restrict__ dvecs,
    float* __restrict__ c_hatT,   // [DIM][NSPK]
    float* __restrict__ loo,      // [NSPK][MU]
    float* __restrict__ inv_e)    // [NSPK][MU]
{
  const int j = blockIdx.x;
  const int t = threadIdx.x;
  __shared__ float sS[DIM];
  __shared__ float sred[4];
  __shared__ float sS2;

  const float* base = dvecs + (size_t)j * (MU * DIM);

  // S = sum over m. thread t owns d = t and d = t+256.
  float s0 = 0.f, s1 = 0.f;
  for (int m = 0; m < MU; ++m) {
    s0 += base[m * DIM + t];
    s1 += base[m * DIM + t + 256];
  }
  sS[t] = s0;
  sS[t + 256] = s1;
  __syncthreads();

  // |S|^2 block reduction
  float p = s0 * s0 + s1 * s1;
  for (int off = 32; off; off >>= 1) p += __shfl_down(p, off);
  if ((t & 63) == 0) sred[t >> 6] = p;
  __syncthreads();
  if (t == 0) sS2 = sred[0] + sred[1] + sred[2] + sred[3];
  __syncthreads();
  const float S2 = sS2;

  // per-utterance dot(e,S) and |e|^2: 8 lanes per m
  const int g = t >> 3;   // m index 0..31
  const int l = t & 7;
  const float* row = base + g * DIM;
  float dotS = 0.f, e2 = 0.f;
  for (int i = 0; i < DIM / 8; ++i) {
    const int d = i * 8 + l;
    const float ev = row[d];
    dotS += ev * sS[d];
    e2 += ev * ev;
  }
  for (int off = 4; off; off >>= 1) {
    dotS += __shfl_down(dotS, off);
    e2 += __shfl_down(e2, off);
  }
  if (l == 0) {
    // loo_cos = (e.S - |e|^2) / (|e| * |S - e|)   ((M-1) factors cancel)
    const float numer = dotS - e2;
    const float d2 = fmaxf(S2 - 2.f * dotS + e2, 0.f);
    loo[j * MU + g] = numer / (sqrtf(e2) * sqrtf(d2));
    inv_e[j * MU + g] = 1.f / sqrtf(e2);
  }

  // normalized centroid, transposed: c_hatT[d][j] = S[d]/|S|
  const float inv_cn = 1.f / sqrtf(S2);
  c_hatT[(size_t)t * NSPK + j] = sS[t] * inv_cn;
  c_hatT[(size_t)(t + 256) * NSPK + j] = sS[t + 256] * inv_cn;
}

// ---------------------------------------------------------------------------
// Kernel 2: fused cosine-GEMM + diag replacement + affine + logsumexp + loss.
// grid = NSPK (one block per speaker j), block = 256.
// Thread (tm,tk) with tm=t>>5 (8 groups), tk=t&31 computes a 4m x 4k tile.
// k-tiles of 128 columns, 8 iterations cover all 1024 centroids.
// ---------------------------------------------------------------------------
__global__ __launch_bounds__(256) void k_loss(
    const float* __restrict__ dvecs,
    const float* __restrict__ c_hatT,
    const float* __restrict__ loo,
    const float* __restrict__ inv_e,
    const float* __restrict__ wptr,
    const float* __restrict__ bptr,
    float* __restrict__ partials)
{
  const int j = blockIdx.x;
  const int t = threadIdx.x;
  __shared__ float sE[MU][DIM];      // normalized utterance rows, 64 KiB
  __shared__ float sSum[MU][33];     // per-(m,tk) partial sumexp
  __shared__ float sTgt[MU];
  __shared__ float sRow[MU];

  const float w = *wptr;
  const float bb = *bptr;
  const float shift = w + bb;        // cos<=1 (clamped >=eps) -> val <= w+b

  const float* base = dvecs + (size_t)j * (MU * DIM);

  // stage normalized e_hat rows
  float* sEf = &sE[0][0];
  for (int idx = t; idx < MU * DIM; idx += 256) {
    const int m = idx >> 9;
    sEf[idx] = base[idx] * inv_e[j * MU + m];
  }
  __syncthreads();

  const int tk = t & 31;
  const int tm = t >> 5;
  float sumexp[4] = {0.f, 0.f, 0.f, 0.f};

  for (int kt = 0; kt < 8; ++kt) {
    const int kb = kt * 128 + tk * 4;
    float acc[4][4] = {{0.f}};
    const float* cp = c_hatT + kb;

#pragma unroll 2
    for (int d = 0; d < DIM; d += 4) {
      const float4 b0 = *(const float4*)(cp + (size_t)(d + 0) * NSPK);
      const float4 b1 = *(const float4*)(cp + (size_t)(d + 1) * NSPK);
      const float4 b2 = *(const float4*)(cp + (size_t)(d + 2) * NSPK);
      const float4 b3 = *(const float4*)(cp + (size_t)(d + 3) * NSPK);
#pragma unroll
      for (int mi = 0; mi < 4; ++mi) {
        const float4 a = *(const float4*)&sE[tm * 4 + mi][d];
        acc[mi][0] += a.x * b0.x + a.y * b1.x + a.z * b2.x + a.w * b3.x;
        acc[mi][1] += a.x * b0.y + a.y * b1.y + a.z * b2.y + a.w * b3.y;
        acc[mi][2] += a.x * b0.z + a.y * b1.z + a.z * b2.z + a.w * b3.z;
        acc[mi][3] += a.x * b0.w + a.y * b1.w + a.z * b2.w + a.w * b3.w;
      }
    }

#pragma unroll
    for (int mi = 0; mi < 4; ++mi) {
      const int m = tm * 4 + mi;
#pragma unroll
      for (int ki = 0; ki < 4; ++ki) {
        const int k = kb + ki;
        float c = acc[mi][ki];
        if (k == j) c = loo[j * MU + m];
        const float val = fmaxf(c, EPS) * w + bb;
        if (k == j) sTgt[m] = val;
        sumexp[mi] += expf(val - shift);
      }
    }
  }

#pragma unroll
  for (int mi = 0; mi < 4; ++mi) sSum[tm * 4 + mi][tk] = sumexp[mi];
  __syncthreads();

  if (t < MU) {
    float s = 0.f;
    for (int i = 0; i < 32; ++i) s += sSum[t][i];
    sRow[t] = logf(s) + shift - sTgt[t];
  }
  __syncthreads();

  if (t == 0) {
    float tot = 0.f;
    for (int m = 0; m < MU; ++m) tot += sRow[m];
    partials[j] = tot;
  }
}

// ---------------------------------------------------------------------------
// Kernel 3: reduce per-speaker partials -> scalar loss
// ---------------------------------------------------------------------------
__global__ __launch_bounds__(256) void k_reduce(
    const float* __restrict__ partials, float* __restrict__ out)
{
  const int t = threadIdx.x;
  __shared__ float r[4];
  float s = 0.f;
  for (int i = t; i < NSPK; i += 256) s += partials[i];
  for (int off = 32; off; off >>= 1) s += __shfl_down(s, off);
  if ((t & 63) == 0) r[t >> 6] = s;
  __syncthreads();
  if (t == 0) out[0] = r[0] + r[1] + r[2] + r[3];
}

extern "C" void kernel_launch(void* const* d_in, const int* in_sizes, int n_in,
                              void* d_out, int out_size, void* d_ws, size_t ws_size,
                              hipStream_t stream) {
  const float* dvecs = (const float*)d_in[0];
  const float* wptr  = (const float*)d_in[1];
  const float* bptr  = (const float*)d_in[2];
  float* out = (float*)d_out;

  // workspace layout (floats)
  float* ws = (float*)d_ws;
  float* c_hatT   = ws;                                   // DIM*NSPK
  float* loo      = c_hatT + (size_t)DIM * NSPK;          // NSPK*MU
  float* inv_e    = loo + NSPK * MU;                      // NSPK*MU
  float* partials = inv_e + NSPK * MU;                    // NSPK

  k_prep<<<NSPK, 256, 0, stream>>>(dvecs, c_hatT, loo, inv_e);
  k_loss<<<NSPK, 256, 0, stream>>>(dvecs, c_hatT, loo, inv_e, wptr, bptr, partials);
  k_reduce<<<1, 256, 0, stream>>>(partials, out);
}

// Round 2
// 109.347 us; speedup vs baseline: 5.3476x; 5.3476x over previous
//
#include <hip/hip_runtime.h>
#include <hip/hip_bf16.h>

#define NSPK 1024
#define MU 32
#define DIM 512
#define NROW (NSPK * MU)   // 32768
#define EPS 1e-6f

#define BM 128
#define BN 128
#define BK 64
#define KSTEPS (DIM / BK)  // 8

typedef __attribute__((ext_vector_type(4))) float f32x4;
typedef __attribute__((ext_vector_type(8))) short bf16x8;

#define GLOAD_LDS16(g, l)                                          \
  __builtin_amdgcn_global_load_lds(                                \
      (const __attribute__((address_space(1))) void*)(g),          \
      (__attribute__((address_space(3))) void*)(l), 16, 0, 0)

// ---------------------------------------------------------------------------
// Kernel 1: per-speaker prep. Writes LOO cosines (fp32, full precision) and
// normalized bf16 copies of utterance rows (A) and centroids (B, row-major).
// grid = NSPK, block = 256
// ---------------------------------------------------------------------------
__global__ __launch_bounds__(256) void k_prep(
    const float* __restrict__ dvecs,
    __hip_bfloat16* __restrict__ Abf,   // [NROW][DIM] normalized rows
    __hip_bfloat16* __restrict__ Bbf,   // [NSPK][DIM] normalized centroids
    float* __restrict__ loo)            // [NROW]
{
  const int j = blockIdx.x;
  const int t = threadIdx.x;
  __shared__ float sS[DIM];
  __shared__ float sred[4];
  __shared__ float sS2;
  __shared__ float sInv[MU];

  const float* base = dvecs + (size_t)j * (MU * DIM);

  // column sums S over the 32 utterances
  float s0 = 0.f, s1 = 0.f;
  for (int m = 0; m < MU; ++m) {
    s0 += base[m * DIM + t];
    s1 += base[m * DIM + t + 256];
  }
  sS[t] = s0;
  sS[t + 256] = s1;
  __syncthreads();

  // |S|^2
  float p = s0 * s0 + s1 * s1;
  for (int off = 32; off; off >>= 1) p += __shfl_down(p, off);
  if ((t & 63) == 0) sred[t >> 6] = p;
  __syncthreads();
  if (t == 0) sS2 = sred[0] + sred[1] + sred[2] + sred[3];
  __syncthreads();
  const float S2 = sS2;

  // per-utterance |e|^2 and dot(e,S); 8 lanes per row
  const int g = t >> 3;
  const int l = t & 7;
  const float* row = base + g * DIM;
  float dotS = 0.f, e2 = 0.f;
  for (int i = 0; i < DIM / 8; ++i) {
    const int d = i * 8 + l;
    const float ev = row[d];
    dotS += ev * sS[d];
    e2 += ev * ev;
  }
  for (int off = 4; off; off >>= 1) {
    dotS += __shfl_down(dotS, off);
    e2 += __shfl_down(e2, off);
  }
  if (l == 0) {
    const float numer = dotS - e2;                       // e.(S-e)
    const float d2 = fmaxf(S2 - 2.f * dotS + e2, 1e-30f); // |S-e|^2
    loo[j * MU + g] = numer / (sqrtf(e2) * sqrtf(d2));
    sInv[g] = 1.f / sqrtf(e2);
  }

  // normalized centroid row (bf16)
  const float invc = 1.f / sqrtf(S2);
  Bbf[(size_t)j * DIM + t] = __float2bfloat16(sS[t] * invc);
  Bbf[(size_t)j * DIM + t + 256] = __float2bfloat16(sS[t + 256] * invc);
  __syncthreads();

  // normalized utterance rows (bf16), pairwise for 4B stores
  __hip_bfloat16* arow = Abf + (size_t)j * (MU * DIM);
  for (int idx = t * 2; idx < MU * DIM; idx += 512) {
    const float inv = sInv[idx >> 9];
    const float2 v = *(const float2*)(base + idx);
    __hip_bfloat162 h;
    h.x = __float2bfloat16(v.x * inv);
    h.y = __float2bfloat16(v.y * inv);
    *(__hip_bfloat162*)(arow + idx) = h;
  }
}

// ---------------------------------------------------------------------------
// Kernel 2: bf16 MFMA NT-GEMM (cos = A . B^T) fused with diag substitution,
// affine, exp, and per-row partial sumexp.
// grid = (8 col-blocks, 256 row-blocks), block = 256 (4 waves, 2x2 of 64x64).
// LDS tiles [128][64] bf16 with q ^= (row&7) XOR swizzle (both sides).
// ---------------------------------------------------------------------------
__global__ __launch_bounds__(256) void k_gemm(
    const ushort* __restrict__ A,     // [NROW][DIM] bf16
    const ushort* __restrict__ B,     // [NSPK][DIM] bf16
    const float* __restrict__ loo,
    const float* __restrict__ wp, const float* __restrict__ bp,
    float* __restrict__ part)         // [8][NROW]
{
  __shared__ ushort ldsA[BM * BK];    // 16 KiB, swizzled
  __shared__ ushort ldsB[BN * BK];    // 16 KiB, swizzled
  __shared__ float sPart[BM][2];

  const int t = threadIdx.x;
  const int cblk = blockIdx.x;        // 0..7
  const int rblk = blockIdx.y;        // 0..255
  const int r0 = rblk * BM, c0 = cblk * BN;
  const int lane = t & 63, w = t >> 6;
  const int wm = w >> 1, wn = w & 1;
  const int lr = lane & 15, lk = lane >> 4;

  const float W = *wp, Bc = *bp, shift = W + Bc;  // cos<=1 -> val<=w+b

  f32x4 acc[4][4];
#pragma unroll
  for (int i = 0; i < 4; ++i)
#pragma unroll
    for (int j2 = 0; j2 < 4; ++j2) acc[i][j2] = (f32x4)0.f;

  for (int kt = 0; kt < KSTEPS; ++kt) {
    const ushort* ga = A + (size_t)r0 * DIM + kt * BK;
    const ushort* gb = B + (size_t)c0 * DIM + kt * BK;
#pragma unroll
    for (int i = 0; i < 4; ++i) {
      const int e = i * 256 + t;
      const int row = e >> 3;
      const int q = (e & 7) ^ (row & 7);   // inverse-swizzled source
      GLOAD_LDS16(ga + row * DIM + q * 8, &ldsA[e * 8]);
      GLOAD_LDS16(gb + row * DIM + q * 8, &ldsB[e * 8]);
    }
    __syncthreads();   // compiler drains vmcnt before barrier -> tiles ready

#pragma unroll
    for (int kk = 0; kk < 2; ++kk) {
      bf16x8 af[4], bfr[4];
#pragma unroll
      for (int mt = 0; mt < 4; ++mt) {
        const int row = wm * 64 + mt * 16 + lr;
        const int q = kk * 4 + lk;
        const int slot = row * 8 + (q ^ (row & 7));   // swizzled read
        af[mt] = *(const bf16x8*)&ldsA[slot * 8];
      }
#pragma unroll
      for (int nt = 0; nt < 4; ++nt) {
        const int row = wn * 64 + nt * 16 + lr;
        const int q = kk * 4 + lk;
        const int slot = row * 8 + (q ^ (row & 7));
        bfr[nt] = *(const bf16x8*)&ldsB[slot * 8];
      }
#pragma unroll
      for (int mt = 0; mt < 4; ++mt)
#pragma unroll
        for (int nt = 0; nt < 4; ++nt)
          acc[mt][nt] = __builtin_amdgcn_mfma_f32_16x16x32_bf16(
              af[mt], bfr[nt], acc[mt][nt], 0, 0, 0);
    }
    __syncthreads();   // protect LDS overwrite next iteration
  }

  // fused epilogue: C/D layout col=lane&15, row=(lane>>4)*4+reg
#pragma unroll
  for (int mt = 0; mt < 4; ++mt)
#pragma unroll
    for (int i = 0; i < 4; ++i) {
      const int row_g = r0 + wm * 64 + mt * 16 + lk * 4 + i;
      const int spk = row_g >> 5;
      float s = 0.f;
#pragma unroll
      for (int nt = 0; nt < 4; ++nt) {
        const int col_g = c0 + wn * 64 + nt * 16 + lr;
        float c = acc[mt][nt][i];
        if (col_g == spk) c = loo[row_g];   // leave-one-out substitution
        const float val = fmaxf(c, EPS) * W + Bc;
        s += expf(val - shift);
      }
      // reduce over the 16 lr-lanes (64 cols of this wave)
      s += __shfl_xor(s, 1);
      s += __shfl_xor(s, 2);
      s += __shfl_xor(s, 4);
      s += __shfl_xor(s, 8);
      if (lr == 0) sPart[wm * 64 + mt * 16 + lk * 4 + i][wn] = s;
    }
  __syncthreads();
  if (t < BM)
    part[(size_t)cblk * NROW + r0 + t] = sPart[t][0] + sPart[t][1];
}

// ---------------------------------------------------------------------------
// Final: per-row logsumexp close + deterministic 2-stage sum
// ---------------------------------------------------------------------------
__global__ __launch_bounds__(256) void k_final1(
    const float* __restrict__ part, const float* __restrict__ loo,
    const float* __restrict__ wp, const float* __restrict__ bp,
    float* __restrict__ p2)
{
  const int t = threadIdx.x;
  const int r = blockIdx.x * 256 + t;
  const float W = *wp, Bc = *bp, shift = W + Bc;
  float s = 0.f;
#pragma unroll
  for (int c = 0; c < 8; ++c) s += part[(size_t)c * NROW + r];
  const float tgt = fmaxf(loo[r], EPS) * W + Bc;
  float v = logf(s) + shift - tgt;
  __shared__ float red[4];
  for (int off = 32; off; off >>= 1) v += __shfl_down(v, off);
  if ((t & 63) == 0) red[t >> 6] = v;
  __syncthreads();
  if (t == 0) p2[blockIdx.x] = red[0] + red[1] + red[2] + red[3];
}

__global__ __launch_bounds__(128) void k_final2(
    const float* __restrict__ p2, float* __restrict__ out)
{
  const int t = threadIdx.x;
  float v = p2[t];
  for (int off = 32; off; off >>= 1) v += __shfl_down(v, off);
  __shared__ float red[2];
  if ((t & 63) == 0) red[t >> 6] = v;
  __syncthreads();
  if (t == 0) out[0] = red[0] + red[1];
}

extern "C" void kernel_launch(void* const* d_in, const int* in_sizes, int n_in,
                              void* d_out, int out_size, void* d_ws, size_t ws_size,
                              hipStream_t stream) {
  const float* dvecs = (const float*)d_in[0];
  const float* wptr  = (const float*)d_in[1];
  const float* bptr  = (const float*)d_in[2];
  float* out = (float*)d_out;

  // workspace layout
  char* ws = (char*)d_ws;
  __hip_bfloat16* Abf = (__hip_bfloat16*)ws;                 // 32 MiB
  ws += (size_t)NROW * DIM * sizeof(__hip_bfloat16);
  __hip_bfloat16* Bbf = (__hip_bfloat16*)ws;                 // 1 MiB
  ws += (size_t)NSPK * DIM * sizeof(__hip_bfloat16);
  float* loo = (float*)ws;                                   // 128 KiB
  ws += (size_t)NROW * sizeof(float);
  float* part = (float*)ws;                                  // 1 MiB
  ws += (size_t)8 * NROW * sizeof(float);
  float* p2 = (float*)ws;                                    // 512 B

  k_prep<<<NSPK, 256, 0, stream>>>(dvecs, Abf, Bbf, loo);
  dim3 g2(8, 256);
  k_gemm<<<g2, 256, 0, stream>>>((const ushort*)Abf, (const ushort*)Bbf,
                                 loo, wptr, bptr, part);
  k_final1<<<NROW / 256, 256, 0, stream>>>(part, loo, wptr, bptr, p2);
  k_final2<<<1, 128, 0, stream>>>(p2, out);
}

// Round 3
// 77.686 us; speedup vs baseline: 7.5270x; 1.4076x over previous
//
#include <hip/hip_runtime.h>
#include <hip/hip_bf16.h>

#define NSPK 1024
#define MU 32
#define DIM 512
#define DIMP (DIM + 8)
#define NROW (NSPK * MU)   // 32768
#define EPS 1e-6f

typedef __attribute__((ext_vector_type(4))) float f32x4;
typedef __attribute__((ext_vector_type(8))) short bf16x8;

#define GLOAD_LDS16(g, l)                                          \
  __builtin_amdgcn_global_load_lds(                                \
      (const __attribute__((address_space(1))) void*)(g),          \
      (__attribute__((address_space(3))) void*)(l), 16, 0, 0)

__device__ inline ushort f2bf(float x) {
  __hip_bfloat16 h = __float2bfloat16(x);
  return *reinterpret_cast<ushort*>(&h);
}

// ---------------------------------------------------------------------------
// Kernel 1: per-speaker prep. LOO cosines (fp32 exact) + normalized bf16
// A and B written in MFMA-FRAGMENT-MAJOR layout:
//   frag(rb,kf) [A] / frag(nb,kf) [B] = 512 ushorts; lane l holds
//   row/col = base16 + (l&15), k = kf*32 + (l>>4)*8 .. +8   (16 B chunk)
// grid = NSPK, block = 256
// ---------------------------------------------------------------------------
__global__ __launch_bounds__(256) void k_prep(
    const float* __restrict__ dvecs,
    ushort* __restrict__ Af,    // [2048 rb][16 kf][64 lane][8]
    ushort* __restrict__ Bf,    // [64 nb][16 kf][64 lane][8]
    float* __restrict__ loo)    // [NROW]
{
  const int j = blockIdx.x, t = threadIdx.x;
  __shared__ float sD[MU * DIMP];   // padded raw speaker rows (66.5 KiB)
  __shared__ float sS[DIM];
  __shared__ float sred[4];
  __shared__ float sS2v;
  __shared__ float sInv[MU];

  const float* base = dvecs + (size_t)j * (MU * DIM);

  // single global read: stage rows + column sums
  float s0 = 0.f, s1 = 0.f;
  for (int m = 0; m < MU; ++m) {
    float a = base[m * DIM + t];
    float b = base[m * DIM + t + 256];
    sD[m * DIMP + t] = a;
    sD[m * DIMP + t + 256] = b;
    s0 += a; s1 += b;
  }
  sS[t] = s0; sS[t + 256] = s1;
  __syncthreads();

  // |S|^2
  float p = s0 * s0 + s1 * s1;
  for (int off = 32; off; off >>= 1) p += __shfl_down(p, off);
  if ((t & 63) == 0) sred[t >> 6] = p;
  __syncthreads();
  if (t == 0) sS2v = sred[0] + sred[1] + sred[2] + sred[3];
  __syncthreads();
  const float S2 = sS2v;

  // per-utterance dot(e,S), |e|^2 from LDS (8 lanes per row)
  const int g = t >> 3, l = t & 7;
  float dotS = 0.f, e2 = 0.f;
  for (int i = 0; i < DIM / 8; ++i) {
    int d = i * 8 + l;
    float ev = sD[g * DIMP + d];
    dotS += ev * sS[d];
    e2 += ev * ev;
  }
  for (int off = 4; off; off >>= 1) {
    dotS += __shfl_down(dotS, off);
    e2 += __shfl_down(e2, off);
  }
  if (l == 0) {
    float numer = dotS - e2;                          // e.(S-e)
    float d2 = fmaxf(S2 - 2.f * dotS + e2, 1e-30f);   // |S-e|^2
    loo[j * MU + g] = numer / (sqrtf(e2) * sqrtf(d2));
    sInv[g] = 1.f / sqrtf(e2);
  }
  __syncthreads();

  // A fragments: this speaker = rows j*32..+31 = rb j*2, j*2+1
  for (int i = 0; i < 8; ++i) {
    int idx = i * 256 + t;          // 0..2047 16B-chunks
    int fragL = idx >> 6;           // 0..31 (rbl*16 + kf)
    int lane2 = idx & 63;
    int rbl = fragL >> 4, kf = fragL & 15;
    int m = rbl * 16 + (lane2 & 15);
    int k0 = kf * 32 + (lane2 >> 4) * 8;
    float inv = sInv[m];
    ushort tmp[8];
#pragma unroll
    for (int z = 0; z < 8; ++z) tmp[z] = f2bf(sD[m * DIMP + k0 + z] * inv);
    *(bf16x8*)&Af[(((size_t)(j * 2 + rbl) * 16 + kf) << 9) + lane2 * 8] =
        *(bf16x8*)tmp;
  }

  // B fragment pieces for centroid j (col j -> lane&15 = j&15)
  if (t < 64) {
    int kf = t >> 2, q = t & 3;
    int lane2 = q * 16 + (j & 15);
    float invc = 1.f / sqrtf(S2);
    int k0 = kf * 32 + q * 8;
    ushort tmp[8];
#pragma unroll
    for (int z = 0; z < 8; ++z) tmp[z] = f2bf(sS[k0 + z] * invc);
    *(bf16x8*)&Bf[(((size_t)(j >> 4) * 16 + kf) << 9) + lane2 * 8] =
        *(bf16x8*)tmp;
  }
}

// ---------------------------------------------------------------------------
// Kernel 2: barrier-free fused cosine-GEMM. One block = 128 rows x ALL 1024
// cols. A panel resident in LDS (staged once, frag-linear, conflict-free
// reads); B fragments streamed global->registers (L2-resident). Fused
// exp-sum epilogue; diag cos captured via wave-uniform scalar branch.
// grid = 256, block = 256 (4 waves, each: all 8 m-frags x 4 n-frags/chunk)
// ---------------------------------------------------------------------------
__global__ __launch_bounds__(256, 1) void k_gemm(
    const ushort* __restrict__ Af,
    const ushort* __restrict__ Bf,
    const float* __restrict__ wp,
    float* __restrict__ part,    // [NROW] sum of exp over all 1024 cols
    float* __restrict__ diag)    // [NROW] raw cos vs own full centroid
{
  __shared__ ushort ldsA[128 * DIM];   // 128 KiB, fragment-linear
  __shared__ float sPart[128][4];

  const int t = threadIdx.x;
  const int w = t >> 6, lane = t & 63;
  const int lr = lane & 15, lk = lane >> 4;
  const int rblk = blockIdx.x;
  const float W = *wp;

  // stage A panel once: 128 frags x 1 KiB, linear global_load_lds
  {
    const ushort* gsrc = Af + (size_t)rblk * (128 * DIM);
    const int off = w * 16384 + lane * 8;   // ushort units
#pragma unroll
    for (int i = 0; i < 32; ++i)
      GLOAD_LDS16(gsrc + off + i * 512, ((char*)ldsA) + (off + i * 512) * 2);
  }
  __syncthreads();   // only barrier before epilogue

  float sum[8][4];
#pragma unroll
  for (int a = 0; a < 8; ++a)
#pragma unroll
    for (int b = 0; b < 4; ++b) sum[a][b] = 0.f;

  for (int c = 0; c < 4; ++c) {            // 4 chunks of 256 cols
    f32x4 acc[8][4];
#pragma unroll
    for (int a = 0; a < 8; ++a)
#pragma unroll
      for (int b = 0; b < 4; ++b) acc[a][b] = (f32x4)0.f;

    // wave's 4 n-frags start at nb0 = c*16 + w*4 ; frag stride 512 ushorts
    const ushort* bp0 = Bf + ((size_t)(c * 16 + w * 4) << 13) + lane * 8;

#pragma unroll 2
    for (int kf = 0; kf < 16; ++kf) {
      bf16x8 bfr[4];
#pragma unroll
      for (int nf = 0; nf < 4; ++nf)
        bfr[nf] = *(const bf16x8*)(bp0 + (nf * 16 + kf) * 512);
#pragma unroll
      for (int mf = 0; mf < 8; ++mf) {
        bf16x8 afr = *(const bf16x8*)&ldsA[((mf * 16 + kf) << 9) + lane * 8];
#pragma unroll
        for (int nf = 0; nf < 4; ++nf)
          acc[mf][nf] = __builtin_amdgcn_mfma_f32_16x16x32_bf16(
              afr, bfr[nf], acc[mf][nf], 0, 0, 0);
      }
    }

    // fused epilogue: exp((fmax(cos,eps)-1)*W)  [shift w+b cancels in lse]
#pragma unroll
    for (int mf = 0; mf < 8; ++mf)
#pragma unroll
      for (int i = 0; i < 4; ++i) {
#pragma unroll
        for (int nf = 0; nf < 4; ++nf)
          sum[mf][i] += __expf((fmaxf(acc[mf][nf][i], EPS) - 1.f) * W);
      }

    // diag capture: block's speakers rblk*4..+3; wave-uniform guards
#pragma unroll
    for (int sp = 0; sp < 4; ++sp) {
      const int s = rblk * 4 + sp;
      const int rel = s - (c * 256 + w * 64);
      if (rel >= 0 && rel < 64 && lr == (s & 15)) {
#pragma unroll
        for (int nf = 0; nf < 4; ++nf) {
          if ((rel >> 4) == nf) {
#pragma unroll
            for (int mh = 0; mh < 2; ++mh)
#pragma unroll
              for (int i = 0; i < 4; ++i)
                diag[s * 32 + mh * 16 + lk * 4 + i] =
                    acc[sp * 2 + mh][nf][i];
          }
        }
      }
    }
  }

  // reduce each row-sum across the 16 lr-lanes (rows differ per lk half)
#pragma unroll
  for (int mf = 0; mf < 8; ++mf)
#pragma unroll
    for (int i = 0; i < 4; ++i) {
      float v = sum[mf][i];
      v += __shfl_xor(v, 1);
      v += __shfl_xor(v, 2);
      v += __shfl_xor(v, 4);
      v += __shfl_xor(v, 8);
      sum[mf][i] = v;
    }
  if (lr == 0) {
#pragma unroll
    for (int mf = 0; mf < 8; ++mf)
#pragma unroll
      for (int i = 0; i < 4; ++i)
        sPart[mf * 16 + lk * 4 + i][w] = sum[mf][i];
  }
  __syncthreads();
  if (t < 128)
    part[rblk * 128 + t] =
        sPart[t][0] + sPart[t][1] + sPart[t][2] + sPart[t][3];
}

// ---------------------------------------------------------------------------
// Final: swap exp(diag)->exp(loo), close logsumexp, deterministic 2-stage sum
// L_row = log(part - exp(dt) + exp(lt)) - lt,  x_t = (fmax(x,eps)-1)*W
// ---------------------------------------------------------------------------
__global__ __launch_bounds__(256) void k_final1(
    const float* __restrict__ part, const float* __restrict__ loo,
    const float* __restrict__ diag, const float* __restrict__ wp,
    float* __restrict__ p2)
{
  const int t = threadIdx.x;
  const int r = blockIdx.x * 256 + t;
  const float W = *wp;
  const float lt = (fmaxf(loo[r], EPS) - 1.f) * W;
  const float dt = (fmaxf(diag[r], EPS) - 1.f) * W;
  const float s = part[r] + __expf(lt) - __expf(dt);
  float v = logf(s) - lt;
  __shared__ float red[4];
  for (int off = 32; off; off >>= 1) v += __shfl_down(v, off);
  if ((t & 63) == 0) red[t >> 6] = v;
  __syncthreads();
  if (t == 0) p2[blockIdx.x] = red[0] + red[1] + red[2] + red[3];
}

__global__ __launch_bounds__(128) void k_final2(
    const float* __restrict__ p2, float* __restrict__ out)
{
  const int t = threadIdx.x;
  float v = p2[t];
  for (int off = 32; off; off >>= 1) v += __shfl_down(v, off);
  __shared__ float red[2];
  if ((t & 63) == 0) red[t >> 6] = v;
  __syncthreads();
  if (t == 0) out[0] = red[0] + red[1];
}

extern "C" void kernel_launch(void* const* d_in, const int* in_sizes, int n_in,
                              void* d_out, int out_size, void* d_ws, size_t ws_size,
                              hipStream_t stream) {
  const float* dvecs = (const float*)d_in[0];
  const float* wptr  = (const float*)d_in[1];
  // b cancels algebraically (shift = w+b subtracted and re-added) -> unused
  float* out = (float*)d_out;

  char* ws = (char*)d_ws;
  ushort* Af = (ushort*)ws;  ws += (size_t)NROW * DIM * sizeof(ushort); // 32 MiB
  ushort* Bf = (ushort*)ws;  ws += (size_t)NSPK * DIM * sizeof(ushort); // 1 MiB
  float* loo  = (float*)ws;  ws += (size_t)NROW * sizeof(float);
  float* diag = (float*)ws;  ws += (size_t)NROW * sizeof(float);
  float* part = (float*)ws;  ws += (size_t)NROW * sizeof(float);
  float* p2   = (float*)ws;

  k_prep<<<NSPK, 256, 0, stream>>>(dvecs, Af, Bf, loo);
  k_gemm<<<256, 256, 0, stream>>>(Af, Bf, wptr, part, diag);
  k_final1<<<NROW / 256, 256, 0, stream>>>(part, loo, diag, wptr, p2);
  k_final2<<<1, 128, 0, stream>>>(p2, out);
}

// Round 4
// 77.207 us; speedup vs baseline: 7.5736x; 1.0062x over previous
//
#include <hip/hip_runtime.h>
#include <hip/hip_bf16.h>

#define NSPK 1024
#define MU 32
#define DIM 512
#define DIMP (DIM + 8)
#define NROW (NSPK * MU)   // 32768
#define EPS 1e-6f

typedef __attribute__((ext_vector_type(4))) float f32x4;
typedef __attribute__((ext_vector_type(8))) short bf16x8;

#define GLOAD_LDS16(g, l)                                          \
  __builtin_amdgcn_global_load_lds(                                \
      (const __attribute__((address_space(1))) void*)(g),          \
      (__attribute__((address_space(3))) void*)(l), 16, 0, 0)

__device__ inline ushort f2bf(float x) {
  __hip_bfloat16 h = __float2bfloat16(x);
  return *reinterpret_cast<ushort*>(&h);
}

// ---------------------------------------------------------------------------
// Kernel 1: per-speaker prep. LOO cosines (fp32 exact) + normalized bf16
// A and B written in MFMA-FRAGMENT-MAJOR layout:
//   frag(rb,kf) [A] / frag(nb,kf) [B] = 512 ushorts; lane l holds
//   row/col = base16 + (l&15), k = kf*32 + (l>>4)*8 .. +8   (16 B chunk)
// grid = NSPK, block = 256
// ---------------------------------------------------------------------------
__global__ __launch_bounds__(256) void k_prep(
    const float* __restrict__ dvecs,
    ushort* __restrict__ Af,    // [2048 rb][16 kf][64 lane][8]
    ushort* __restrict__ Bf,    // [64 nb][16 kf][64 lane][8]
    float* __restrict__ loo)    // [NROW]
{
  const int j = blockIdx.x, t = threadIdx.x;
  __shared__ float sD[MU * DIMP];   // padded raw speaker rows (66.5 KiB)
  __shared__ float sS[DIM];
  __shared__ float sred[4];
  __shared__ float sS2v;
  __shared__ float sInv[MU];

  const float* base = dvecs + (size_t)j * (MU * DIM);

  // single global read: stage rows + column sums
  float s0 = 0.f, s1 = 0.f;
  for (int m = 0; m < MU; ++m) {
    float a = base[m * DIM + t];
    float b = base[m * DIM + t + 256];
    sD[m * DIMP + t] = a;
    sD[m * DIMP + t + 256] = b;
    s0 += a; s1 += b;
  }
  sS[t] = s0; sS[t + 256] = s1;
  __syncthreads();

  // |S|^2
  float p = s0 * s0 + s1 * s1;
  for (int off = 32; off; off >>= 1) p += __shfl_down(p, off);
  if ((t & 63) == 0) sred[t >> 6] = p;
  __syncthreads();
  if (t == 0) sS2v = sred[0] + sred[1] + sred[2] + sred[3];
  __syncthreads();
  const float S2 = sS2v;

  // per-utterance dot(e,S), |e|^2 from LDS (8 lanes per row)
  const int g = t >> 3, l = t & 7;
  float dotS = 0.f, e2 = 0.f;
  for (int i = 0; i < DIM / 8; ++i) {
    int d = i * 8 + l;
    float ev = sD[g * DIMP + d];
    dotS += ev * sS[d];
    e2 += ev * ev;
  }
  for (int off = 4; off; off >>= 1) {
    dotS += __shfl_down(dotS, off);
    e2 += __shfl_down(e2, off);
  }
  if (l == 0) {
    float numer = dotS - e2;                          // e.(S-e)
    float d2 = fmaxf(S2 - 2.f * dotS + e2, 1e-30f);   // |S-e|^2
    loo[j * MU + g] = numer / (sqrtf(e2) * sqrtf(d2));
    sInv[g] = 1.f / sqrtf(e2);
  }
  __syncthreads();

  // A fragments: this speaker = rows j*32..+31 = rb j*2, j*2+1
  for (int i = 0; i < 8; ++i) {
    int idx = i * 256 + t;          // 0..2047 16B-chunks
    int fragL = idx >> 6;           // 0..31 (rbl*16 + kf)
    int lane2 = idx & 63;
    int rbl = fragL >> 4, kf = fragL & 15;
    int m = rbl * 16 + (lane2 & 15);
    int k0 = kf * 32 + (lane2 >> 4) * 8;
    float inv = sInv[m];
    ushort tmp[8];
#pragma unroll
    for (int z = 0; z < 8; ++z) tmp[z] = f2bf(sD[m * DIMP + k0 + z] * inv);
    *(bf16x8*)&Af[(((size_t)(j * 2 + rbl) * 16 + kf) << 9) + lane2 * 8] =
        *(bf16x8*)tmp;
  }

  // B fragment pieces for centroid j (col j -> lane&15 = j&15)
  if (t < 64) {
    int kf = t >> 2, q = t & 3;
    int lane2 = q * 16 + (j & 15);
    float invc = 1.f / sqrtf(S2);
    int k0 = kf * 32 + q * 8;
    ushort tmp[8];
#pragma unroll
    for (int z = 0; z < 8; ++z) tmp[z] = f2bf(sS[k0 + z] * invc);
    *(bf16x8*)&Bf[(((size_t)(j >> 4) * 16 + kf) << 9) + lane2 * 8] =
        *(bf16x8*)tmp;
  }
}

// ---------------------------------------------------------------------------
// Kernel 2: barrier-free fused cosine-GEMM. One block = 128 rows x ALL 1024
// cols; 8 waves (512 thr) = 2 row-groups x 4 col-groups -> 2 waves/SIMD.
// A panel resident in LDS (staged once, frag-linear, conflict-free reads);
// B fragments streamed global->registers (L2-resident), held across 4 mf.
// Wave tile 64r x 256c processed as 2 sub-chunks of 4mf x 8nf (acc=128 VGPR).
// grid = 256, block = 512
// ---------------------------------------------------------------------------
__global__ __launch_bounds__(512, 2) void k_gemm(
    const ushort* __restrict__ Af,
    const ushort* __restrict__ Bf,
    const float* __restrict__ wp,
    float* __restrict__ part,    // [NROW] sum of exp over all 1024 cols
    float* __restrict__ diag)    // [NROW] raw cos vs own full centroid
{
  __shared__ ushort ldsA[128 * DIM];   // 128 KiB, fragment-linear
  __shared__ float sPart[128][4];

  const int t = threadIdx.x;
  const int w = t >> 6, lane = t & 63;
  const int lr = lane & 15, lk = lane >> 4;
  const int wm = w >> 2, wn = w & 3;
  const int rblk = blockIdx.x;
  const float W = *wp;

  // stage A panel once: 128 frags x 1 KiB, linear global_load_lds
  {
    const ushort* gsrc = Af + (size_t)rblk * (128 * DIM);
    const int off = t * 8;   // ushort units, lane-contiguous 16B
#pragma unroll
    for (int i = 0; i < 16; ++i)
      GLOAD_LDS16(gsrc + off + i * 4096, ((char*)ldsA) + (off + i * 4096) * 2);
  }
  __syncthreads();   // only barrier before epilogue

  float sum[4][4];
#pragma unroll
  for (int a = 0; a < 4; ++a)
#pragma unroll
    for (int b = 0; b < 4; ++b) sum[a][b] = 0.f;

#pragma unroll
  for (int sub = 0; sub < 2; ++sub) {
    f32x4 acc[4][8];
#pragma unroll
    for (int a = 0; a < 4; ++a)
#pragma unroll
      for (int b = 0; b < 8; ++b) acc[a][b] = (f32x4)0.f;

    // this sub-chunk's 8 B fragments start at nb0; frag stride 512 ushorts
    const ushort* bp0 = Bf + ((size_t)(wn * 16 + sub * 8) << 13) + lane * 8;

#pragma unroll
    for (int kf = 0; kf < 16; ++kf) {
      bf16x8 bfr[8];
#pragma unroll
      for (int nf = 0; nf < 8; ++nf)
        bfr[nf] = *(const bf16x8*)(bp0 + (size_t)((nf * 16 + kf) << 9));
#pragma unroll
      for (int mf = 0; mf < 4; ++mf) {
        const bf16x8 afr =
            *(const bf16x8*)&ldsA[(((wm * 4 + mf) * 16 + kf) << 9) + lane * 8];
#pragma unroll
        for (int nf = 0; nf < 8; ++nf)
          acc[mf][nf] = __builtin_amdgcn_mfma_f32_16x16x32_bf16(
              afr, bfr[nf], acc[mf][nf], 0, 0, 0);
      }
    }

    // fused epilogue: exp((fmax(cos,eps)-1)*W)  [shift w+b cancels in lse]
#pragma unroll
    for (int mf = 0; mf < 4; ++mf)
#pragma unroll
      for (int i = 0; i < 4; ++i) {
#pragma unroll
        for (int nf = 0; nf < 8; ++nf)
          sum[mf][i] += __expf((fmaxf(acc[mf][nf][i], EPS) - 1.f) * W);
      }

    // diag capture (once per block): col c = rblk*4 + wm*2 + (mf>>1) lives in
    // frag nb = c>>4 -> wn = rblk>>6, sub = (rblk>>5)&1, nf = (rblk>>2)&7
    if (wn == (rblk >> 6) && sub == ((rblk >> 5) & 1)) {
      const int nfo = (rblk >> 2) & 7;
#pragma unroll
      for (int mf = 0; mf < 4; ++mf) {
        const int col = rblk * 4 + wm * 2 + (mf >> 1);
        f32x4 dsel = acc[mf][0];
#pragma unroll
        for (int nf = 1; nf < 8; ++nf)
          if (nf == nfo) dsel = acc[mf][nf];   // static indices only
        if (lr == (col & 15)) {
#pragma unroll
          for (int i = 0; i < 4; ++i)
            diag[rblk * 128 + wm * 64 + mf * 16 + lk * 4 + i] = dsel[i];
        }
      }
    }
  }

  // reduce each row-sum across the 16 lr-lanes
#pragma unroll
  for (int mf = 0; mf < 4; ++mf)
#pragma unroll
    for (int i = 0; i < 4; ++i) {
      float v = sum[mf][i];
      v += __shfl_xor(v, 1);
      v += __shfl_xor(v, 2);
      v += __shfl_xor(v, 4);
      v += __shfl_xor(v, 8);
      sum[mf][i] = v;
    }
  if (lr == 0) {
#pragma unroll
    for (int mf = 0; mf < 4; ++mf)
#pragma unroll
      for (int i = 0; i < 4; ++i)
        sPart[wm * 64 + mf * 16 + lk * 4 + i][wn] = sum[mf][i];
  }
  __syncthreads();
  if (t < 128)
    part[rblk * 128 + t] =
        sPart[t][0] + sPart[t][1] + sPart[t][2] + sPart[t][3];
}

// ---------------------------------------------------------------------------
// Final: swap exp(diag)->exp(loo), close logsumexp, deterministic 2-stage sum
// L_row = log(part - exp(dt) + exp(lt)) - lt,  x_t = (fmax(x,eps)-1)*W
// ---------------------------------------------------------------------------
__global__ __launch_bounds__(256) void k_final1(
    const float* __restrict__ part, const float* __restrict__ loo,
    const float* __restrict__ diag, const float* __restrict__ wp,
    float* __restrict__ p2)
{
  const int t = threadIdx.x;
  const int r = blockIdx.x * 256 + t;
  const float W = *wp;
  const float lt = (fmaxf(loo[r], EPS) - 1.f) * W;
  const float dt = (fmaxf(diag[r], EPS) - 1.f) * W;
  const float s = part[r] + __expf(lt) - __expf(dt);
  float v = logf(s) - lt;
  __shared__ float red[4];
  for (int off = 32; off; off >>= 1) v += __shfl_down(v, off);
  if ((t & 63) == 0) red[t >> 6] = v;
  __syncthreads();
  if (t == 0) p2[blockIdx.x] = red[0] + red[1] + red[2] + red[3];
}

__global__ __launch_bounds__(128) void k_final2(
    const float* __restrict__ p2, float* __restrict__ out)
{
  const int t = threadIdx.x;
  float v = p2[t];
  for (int off = 32; off; off >>= 1) v += __shfl_down(v, off);
  __shared__ float red[2];
  if ((t & 63) == 0) red[t >> 6] = v;
  __syncthreads();
  if (t == 0) out[0] = red[0] + red[1];
}

extern "C" void kernel_launch(void* const* d_in, const int* in_sizes, int n_in,
                              void* d_out, int out_size, void* d_ws, size_t ws_size,
                              hipStream_t stream) {
  const float* dvecs = (const float*)d_in[0];
  const float* wptr  = (const float*)d_in[1];
  // b cancels algebraically (shift = w+b subtracted and re-added) -> unused
  float* out = (float*)d_out;

  char* ws = (char*)d_ws;
  ushort* Af = (ushort*)ws;  ws += (size_t)NROW * DIM * sizeof(ushort); // 32 MiB
  ushort* Bf = (ushort*)ws;  ws += (size_t)NSPK * DIM * sizeof(ushort); // 1 MiB
  float* loo  = (float*)ws;  ws += (size_t)NROW * sizeof(float);
  float* diag = (float*)ws;  ws += (size_t)NROW * sizeof(float);
  float* part = (float*)ws;  ws += (size_t)NROW * sizeof(float);
  float* p2   = (float*)ws;

  k_prep<<<NSPK, 256, 0, stream>>>(dvecs, Af, Bf, loo);
  k_gemm<<<256, 512, 0, stream>>>(Af, Bf, wptr, part, diag);
  k_final1<<<NROW / 256, 256, 0, stream>>>(part, loo, diag, wptr, p2);
  k_final2<<<1, 128, 0, stream>>>(p2, out);
}

// Round 5
// 76.750 us; speedup vs baseline: 7.6187x; 1.0060x over previous
//
#include <hip/hip_runtime.h>
#include <hip/hip_bf16.h>

#define NSPK 1024
#define MU 32
#define DIM 512
#define DIMP (DIM + 8)
#define NROW (NSPK * MU)   // 32768
#define EPS 1e-6f

typedef __attribute__((ext_vector_type(4))) float f32x4;
typedef __attribute__((ext_vector_type(8))) short bf16x8;

#define GLOAD_LDS16(g, l)                                          \
  __builtin_amdgcn_global_load_lds(                                \
      (const __attribute__((address_space(1))) void*)(g),          \
      (__attribute__((address_space(3))) void*)(l), 16, 0, 0)

__device__ inline ushort f2bf(float x) {
  __hip_bfloat16 h = __float2bfloat16(x);
  return *reinterpret_cast<ushort*>(&h);
}

// ---------------------------------------------------------------------------
// Kernel 1: per-speaker prep. LOO cosines (fp32 exact) + normalized bf16
// A and B written in MFMA-FRAGMENT-MAJOR layout:
//   frag(rb,kf) [A] / frag(nb,kf) [B] = 512 ushorts; lane l holds
//   row/col = base16 + (l&15), k = kf*32 + (l>>4)*8 .. +8   (16 B chunk)
// grid = NSPK, block = 256
// ---------------------------------------------------------------------------
__global__ __launch_bounds__(256) void k_prep(
    const float* __restrict__ dvecs,
    ushort* __restrict__ Af,    // [2048 rb][16 kf][64 lane][8]
    ushort* __restrict__ Bf,    // [64 nb][16 kf][64 lane][8]
    float* __restrict__ loo)    // [NROW]
{
  const int j = blockIdx.x, t = threadIdx.x;
  __shared__ float sD[MU * DIMP];   // padded raw speaker rows (66.5 KiB)
  __shared__ float sS[DIM];
  __shared__ float sred[4];
  __shared__ float sS2v;
  __shared__ float sInv[MU];

  const float* base = dvecs + (size_t)j * (MU * DIM);

  // single global read: stage rows + column sums
  float s0 = 0.f, s1 = 0.f;
  for (int m = 0; m < MU; ++m) {
    float a = base[m * DIM + t];
    float b = base[m * DIM + t + 256];
    sD[m * DIMP + t] = a;
    sD[m * DIMP + t + 256] = b;
    s0 += a; s1 += b;
  }
  sS[t] = s0; sS[t + 256] = s1;
  __syncthreads();

  // |S|^2
  float p = s0 * s0 + s1 * s1;
  for (int off = 32; off; off >>= 1) p += __shfl_down(p, off);
  if ((t & 63) == 0) sred[t >> 6] = p;
  __syncthreads();
  if (t == 0) sS2v = sred[0] + sred[1] + sred[2] + sred[3];
  __syncthreads();
  const float S2 = sS2v;

  // per-utterance dot(e,S), |e|^2 from LDS (8 lanes per row)
  const int g = t >> 3, l = t & 7;
  float dotS = 0.f, e2 = 0.f;
  for (int i = 0; i < DIM / 8; ++i) {
    int d = i * 8 + l;
    float ev = sD[g * DIMP + d];
    dotS += ev * sS[d];
    e2 += ev * ev;
  }
  for (int off = 4; off; off >>= 1) {
    dotS += __shfl_down(dotS, off);
    e2 += __shfl_down(e2, off);
  }
  if (l == 0) {
    float numer = dotS - e2;                          // e.(S-e)
    float d2 = fmaxf(S2 - 2.f * dotS + e2, 1e-30f);   // |S-e|^2
    loo[j * MU + g] = numer / (sqrtf(e2) * sqrtf(d2));
    sInv[g] = 1.f / sqrtf(e2);
  }
  __syncthreads();

  // A fragments: this speaker = rows j*32..+31 = rb j*2, j*2+1
  for (int i = 0; i < 8; ++i) {
    int idx = i * 256 + t;          // 0..2047 16B-chunks
    int fragL = idx >> 6;           // 0..31 (rbl*16 + kf)
    int lane2 = idx & 63;
    int rbl = fragL >> 4, kf = fragL & 15;
    int m = rbl * 16 + (lane2 & 15);
    int k0 = kf * 32 + (lane2 >> 4) * 8;
    float inv = sInv[m];
    ushort tmp[8];
#pragma unroll
    for (int z = 0; z < 8; ++z) tmp[z] = f2bf(sD[m * DIMP + k0 + z] * inv);
    *(bf16x8*)&Af[(((size_t)(j * 2 + rbl) * 16 + kf) << 9) + lane2 * 8] =
        *(bf16x8*)tmp;
  }

  // B fragment pieces for centroid j (col j -> lane&15 = j&15)
  if (t < 64) {
    int kf = t >> 2, q = t & 3;
    int lane2 = q * 16 + (j & 15);
    float invc = 1.f / sqrtf(S2);
    int k0 = kf * 32 + q * 8;
    ushort tmp[8];
#pragma unroll
    for (int z = 0; z < 8; ++z) tmp[z] = f2bf(sS[k0 + z] * invc);
    *(bf16x8*)&Bf[(((size_t)(j >> 4) * 16 + kf) << 9) + lane2 * 8] =
        *(bf16x8*)tmp;
  }
}

// ---------------------------------------------------------------------------
// Kernel 2: barrier-free fused cosine-GEMM. One block = 128 rows x ALL 1024
// cols; 8 waves (512 thr) = 2 row-groups x 4 col-groups -> 2 waves/SIMD.
// A panel resident in LDS (staged once, frag-linear, conflict-free reads);
// B fragments streamed global->registers (L2-resident), held across 4 mf.
// Wave tile 64r x 256c processed as 2 sub-chunks of 4mf x 8nf (acc=128 VGPR).
// launch_bounds(512,1): let the allocator take ~220 VGPR (acc+bfr+sum) --
// (512,2) capped it at 128 and spilled the accumulator (69 MB scratch, R4).
// grid = 256, block = 512
// ---------------------------------------------------------------------------
__global__ __launch_bounds__(512, 1) void k_gemm(
    const ushort* __restrict__ Af,
    const ushort* __restrict__ Bf,
    const float* __restrict__ wp,
    float* __restrict__ part,    // [NROW] sum of exp over all 1024 cols
    float* __restrict__ diag)    // [NROW] raw cos vs own full centroid
{
  __shared__ ushort ldsA[128 * DIM];   // 128 KiB, fragment-linear
  __shared__ float sPart[128][4];

  const int t = threadIdx.x;
  const int w = t >> 6, lane = t & 63;
  const int lr = lane & 15, lk = lane >> 4;
  const int wm = w >> 2, wn = w & 3;
  const int rblk = blockIdx.x;
  const float W = *wp;

  // stage A panel once: 128 frags x 1 KiB, linear global_load_lds
  {
    const ushort* gsrc = Af + (size_t)rblk * (128 * DIM);
    const int off = t * 8;   // ushort units, lane-contiguous 16B
#pragma unroll
    for (int i = 0; i < 16; ++i)
      GLOAD_LDS16(gsrc + off + i * 4096, ((char*)ldsA) + (off + i * 4096) * 2);
  }
  __syncthreads();   // only barrier before epilogue

  float sum[4][4];
#pragma unroll
  for (int a = 0; a < 4; ++a)
#pragma unroll
    for (int b = 0; b < 4; ++b) sum[a][b] = 0.f;

#pragma unroll
  for (int sub = 0; sub < 2; ++sub) {
    f32x4 acc[4][8];
#pragma unroll
    for (int a = 0; a < 4; ++a)
#pragma unroll
      for (int b = 0; b < 8; ++b) acc[a][b] = (f32x4)0.f;

    // this sub-chunk's 8 B fragments start at nb0; frag stride 512 ushorts
    const ushort* bp0 = Bf + ((size_t)(wn * 16 + sub * 8) << 13) + lane * 8;

#pragma unroll
    for (int kf = 0; kf < 16; ++kf) {
      bf16x8 bfr[8];
#pragma unroll
      for (int nf = 0; nf < 8; ++nf)
        bfr[nf] = *(const bf16x8*)(bp0 + (size_t)((nf * 16 + kf) << 9));
#pragma unroll
      for (int mf = 0; mf < 4; ++mf) {
        const bf16x8 afr =
            *(const bf16x8*)&ldsA[(((wm * 4 + mf) * 16 + kf) << 9) + lane * 8];
#pragma unroll
        for (int nf = 0; nf < 8; ++nf)
          acc[mf][nf] = __builtin_amdgcn_mfma_f32_16x16x32_bf16(
              afr, bfr[nf], acc[mf][nf], 0, 0, 0);
      }
    }

    // fused epilogue: exp((fmax(cos,eps)-1)*W)  [shift w+b cancels in lse]
#pragma unroll
    for (int mf = 0; mf < 4; ++mf)
#pragma unroll
      for (int i = 0; i < 4; ++i) {
#pragma unroll
        for (int nf = 0; nf < 8; ++nf)
          sum[mf][i] += __expf((fmaxf(acc[mf][nf][i], EPS) - 1.f) * W);
      }

    // diag capture (once per block): col c = rblk*4 + wm*2 + (mf>>1) lives in
    // frag nb = c>>4 -> wn = rblk>>6, sub = (rblk>>5)&1, nf = (rblk>>2)&7
    if (wn == (rblk >> 6) && sub == ((rblk >> 5) & 1)) {
      const int nfo = (rblk >> 2) & 7;
#pragma unroll
      for (int mf = 0; mf < 4; ++mf) {
        const int col = rblk * 4 + wm * 2 + (mf >> 1);
        f32x4 dsel = acc[mf][0];
#pragma unroll
        for (int nf = 1; nf < 8; ++nf)
          if (nf == nfo) dsel = acc[mf][nf];   // static indices only
        if (lr == (col & 15)) {
#pragma unroll
          for (int i = 0; i < 4; ++i)
            diag[rblk * 128 + wm * 64 + mf * 16 + lk * 4 + i] = dsel[i];
        }
      }
    }
  }

  // reduce each row-sum across the 16 lr-lanes
#pragma unroll
  for (int mf = 0; mf < 4; ++mf)
#pragma unroll
    for (int i = 0; i < 4; ++i) {
      float v = sum[mf][i];
      v += __shfl_xor(v, 1);
      v += __shfl_xor(v, 2);
      v += __shfl_xor(v, 4);
      v += __shfl_xor(v, 8);
      sum[mf][i] = v;
    }
  if (lr == 0) {
#pragma unroll
    for (int mf = 0; mf < 4; ++mf)
#pragma unroll
      for (int i = 0; i < 4; ++i)
        sPart[wm * 64 + mf * 16 + lk * 4 + i][wn] = sum[mf][i];
  }
  __syncthreads();
  if (t < 128)
    part[rblk * 128 + t] =
        sPart[t][0] + sPart[t][1] + sPart[t][2] + sPart[t][3];
}

// ---------------------------------------------------------------------------
// Final: swap exp(diag)->exp(loo), close logsumexp, deterministic 2-stage sum
// L_row = log(part - exp(dt) + exp(lt)) - lt,  x_t = (fmax(x,eps)-1)*W
// ---------------------------------------------------------------------------
__global__ __launch_bounds__(256) void k_final1(
    const float* __restrict__ part, const float* __restrict__ loo,
    const float* __restrict__ diag, const float* __restrict__ wp,
    float* __restrict__ p2)
{
  const int t = threadIdx.x;
  const int r = blockIdx.x * 256 + t;
  const float W = *wp;
  const float lt = (fmaxf(loo[r], EPS) - 1.f) * W;
  const float dt = (fmaxf(diag[r], EPS) - 1.f) * W;
  const float s = part[r] + __expf(lt) - __expf(dt);
  float v = logf(s) - lt;
  __shared__ float red[4];
  for (int off = 32; off; off >>= 1) v += __shfl_down(v, off);
  if ((t & 63) == 0) red[t >> 6] = v;
  __syncthreads();
  if (t == 0) p2[blockIdx.x] = red[0] + red[1] + red[2] + red[3];
}

__global__ __launch_bounds__(128) void k_final2(
    const float* __restrict__ p2, float* __restrict__ out)
{
  const int t = threadIdx.x;
  float v = p2[t];
  for (int off = 32; off; off >>= 1) v += __shfl_down(v, off);
  __shared__ float red[2];
  if ((t & 63) == 0) red[t >> 6] = v;
  __syncthreads();
  if (t == 0) out[0] = red[0] + red[1];
}

extern "C" void kernel_launch(void* const* d_in, const int* in_sizes, int n_in,
                              void* d_out, int out_size, void* d_ws, size_t ws_size,
                              hipStream_t stream) {
  const float* dvecs = (const float*)d_in[0];
  const float* wptr  = (const float*)d_in[1];
  // b cancels algebraically (shift = w+b subtracted and re-added) -> unused
  float* out = (float*)d_out;

  char* ws = (char*)d_ws;
  ushort* Af = (ushort*)ws;  ws += (size_t)NROW * DIM * sizeof(ushort); // 32 MiB
  ushort* Bf = (ushort*)ws;  ws += (size_t)NSPK * DIM * sizeof(ushort); // 1 MiB
  float* loo  = (float*)ws;  ws += (size_t)NROW * sizeof(float);
  float* diag = (float*)ws;  ws += (size_t)NROW * sizeof(float);
  float* part = (float*)ws;  ws += (size_t)NROW * sizeof(float);
  float* p2   = (float*)ws;

  k_prep<<<NSPK, 256, 0, stream>>>(dvecs, Af, Bf, loo);
  k_gemm<<<256, 512, 0, stream>>>(Af, Bf, wptr, part, diag);
  k_final1<<<NROW / 256, 256, 0, stream>>>(part, loo, diag, wptr, p2);
  k_final2<<<1, 128, 0, stream>>>(p2, out);
}